// Round 4
// baseline (740.994 us; speedup 1.0000x reference)
//
#include <hip/hip_runtime.h>

typedef unsigned short u16;
typedef short bfrag __attribute__((ext_vector_type(8)));   // 8 bf16 (4 VGPRs)
typedef float facc  __attribute__((ext_vector_type(4)));   // 4 fp32 acc

#define LOG2E 1.44269504088896340736f

static __device__ __forceinline__ u16 f2bf(float x) {  // RNE
  union { float f; unsigned u; } v; v.f = x;
  return (u16)((v.u + 0x7FFFu + ((v.u >> 16) & 1u)) >> 16);
}
static __device__ __forceinline__ void gload_lds16(const u16* g, u16* l) {
  __builtin_amdgcn_global_load_lds((const __attribute__((address_space(1))) void*)g,
                                   (__attribute__((address_space(3))) void*)l,
                                   16, 0, 0);
}
// bias staging: NT cache policy (aux=2) so the 268MB stream doesn't evict K/V from L2
static __device__ __forceinline__ void gload_lds16f_nt(const float* g, float* l) {
  __builtin_amdgcn_global_load_lds((const __attribute__((address_space(1))) void*)g,
                                   (__attribute__((address_space(3))) void*)l,
                                   16, 0, 2);
}

// Kernel 0: f32 -> bf16 RNE pre-convert of x, qkv_w, proj_w (memory-bound, ~48MB)
__global__ __launch_bounds__(256) void convert_kernel(
    const float* __restrict__ x, const float* __restrict__ qw, const float* __restrict__ pw,
    u16* __restrict__ xb, u16* __restrict__ qwb, u16* __restrict__ pwb)
{
  const int NX = 4 * 1024 * 1024, NQ = 3 * 1024 * 1024, NP = 1024 * 1024;
  const int total4 = (NX + NQ + NP) >> 2;
  for (int i = blockIdx.x * blockDim.x + threadIdx.x; i < total4;
       i += gridDim.x * blockDim.x) {
    const int e = i << 2;
    const float* s; u16* d; int off;
    if (e < NX)            { s = x;  d = xb;  off = e; }
    else if (e < NX + NQ)  { s = qw; d = qwb; off = e - NX; }
    else                   { s = pw; d = pwb; off = e - NX - NQ; }
    float4 v = *(const float4*)(s + off);
    ushort4 o;
    o.x = f2bf(v.x); o.y = f2bf(v.y); o.z = f2bf(v.z); o.w = f2bf(v.w);
    *(ushort4*)(d + off) = o;
  }
}

// C[m][n] = sum_k A[m][k] * B[n][k]   (B^T GEMM, bf16). 128x128 tile / 256 thr.
static __device__ __forceinline__ void gemm128_bt(
    const u16* __restrict__ A, const u16* __restrict__ B, int K,
    int m0, int n0, u16* As, u16* Bs, facc acc[4][4])
{
  const int lane = threadIdx.x & 63;
  const int wv   = threadIdx.x >> 6;
  const int quad = lane >> 4;
  const int l15  = lane & 15;
  const int wm = wv >> 1, wn = wv & 1;
  const int srow = lane >> 2;        // 16 rows per wave-call
  const int skb  = (lane & 3) * 8;   // 4 x 8 bf16 = 64B per row

  facc zero = {0.f, 0.f, 0.f, 0.f};
#pragma unroll
  for (int i = 0; i < 4; ++i)
#pragma unroll
    for (int j = 0; j < 4; ++j) acc[i][j] = zero;

  const int nIter = K >> 5;
  for (int kk = 0; kk < nIter; ++kk) {
    const int k0 = kk << 5;
    __syncthreads();                  // previous compute done before LDS overwrite
#pragma unroll
    for (int c = 0; c < 2; ++c) {
      const int seg = wv * 2 + c;     // 8 segs x 16 rows = 128 rows
      gload_lds16(A + (long)(m0 + seg * 16 + srow) * K + k0 + skb, As + seg * 512);
      gload_lds16(B + (long)(n0 + seg * 16 + srow) * K + k0 + skb, Bs + seg * 512);
    }
    __syncthreads();                  // compiler drains vmcnt before barrier
    bfrag af[4], bf[4];
#pragma unroll
    for (int i = 0; i < 4; ++i)
      af[i] = *(const bfrag*)(As + (wm * 64 + i * 16 + l15) * 32 + quad * 8);
#pragma unroll
    for (int j = 0; j < 4; ++j)
      bf[j] = *(const bfrag*)(Bs + (wn * 64 + j * 16 + l15) * 32 + quad * 8);
#pragma unroll
    for (int i = 0; i < 4; ++i)
#pragma unroll
      for (int j = 0; j < 4; ++j)
        acc[i][j] = __builtin_amdgcn_mfma_f32_16x16x32_bf16(af[i], bf[j], acc[i][j], 0, 0, 0);
  }
}

// Kernel 1: qkv = x @ qkv_w^T + qkv_b.  Scatter: Q(scaled) [B,H,N,D], K [B,H,N,D],
// V transposed [B,H,D,N] so PV's B-operand is contiguous.
__global__ __launch_bounds__(256) void qkv_gemm_kernel(
    const u16* __restrict__ x, const u16* __restrict__ w,
    const float* __restrict__ qb, const float* __restrict__ vb,
    u16* __restrict__ Q, u16* __restrict__ Kd, u16* __restrict__ Vt)
{
  __shared__ u16 As[128 * 32];
  __shared__ u16 Bs[128 * 32];
  facc acc[4][4];
  const int m0 = blockIdx.y * 128;   // rows of x (B*N = 4096)
  const int n0 = blockIdx.x * 128;   // cols (3C = 3072)
  gemm128_bt(x, w, 1024, m0, n0, As, Bs, acc);

  const int lane = threadIdx.x & 63;
  const int wv = threadIdx.x >> 6;
  const int quad = lane >> 4, l15 = lane & 15;
  const int wm = wv >> 1, wn = wv & 1;
  const int ncb = n0 + wn * 64;        // wave-uniform: one (which, h) per wave
  const int which = ncb >> 10;         // 0=Q 1=K 2=V
  const int h = (ncb >> 6) & 15;

#pragma unroll
  for (int j = 0; j < 4; ++j) {
    const int d = j * 16 + l15;        // d within head
    const int n_g = ncb + d;
#pragma unroll
    for (int i = 0; i < 4; ++i) {
      const int mg0 = m0 + wm * 64 + i * 16 + quad * 4;   // 4-aligned
      const int b  = mg0 >> 11;
      const int ns = mg0 & 2047;
      if (which == 0) {
        const float qbv = qb[n_g];
#pragma unroll
        for (int r = 0; r < 4; ++r)
          Q[(((long)(b * 16 + h) * 2048 + ns + r) << 6) + d] =
              f2bf((acc[i][j][r] + qbv) * 0.125f);          // (x@W+qb)*SCALE
      } else if (which == 1) {
#pragma unroll
        for (int r = 0; r < 4; ++r)
          Kd[(((long)(b * 16 + h) * 2048 + ns + r) << 6) + d] = f2bf(acc[i][j][r]);
      } else {
        const float vbv = vb[n_g - 2048];
        ushort4 pk;                                          // 4 consecutive n -> 8B store
        pk.x = f2bf(acc[i][j][0] + vbv);
        pk.y = f2bf(acc[i][j][1] + vbv);
        pk.z = f2bf(acc[i][j][2] + vbv);
        pk.w = f2bf(acc[i][j][3] + vbv);
        *(ushort4*)(Vt + (((long)((b * 16 + h) * 64 + d)) << 11) + ns) = pk;
      }
    }
  }
}

// Kernel 2: flash attention, K-split x2, SWAPPED QK^T.
// Block = (h, 32 q-rows, k-half); 4 waves = {b0,b1} x {q-half}.
// S^T = mfma(K,Q): lane (quad,l15) holds scores for q = qw+l15 (ONE row),
// k = kt*16 + quad*4 + r.  Row-softmax = in-lane 16-tree + 2 shfl_xor(16/32);
// m/l/alpha are per-lane scalars.  PV swapped too: O^T = mfma(V^T, P^T).
// P^T LDS slot layout makes the B-frag read exactly PwB + p*1024 + lane*16
// (linear, conflict-free); writes are 4x ds_write_b64.
// Bias: cooperative LDS staging (batch pair shares head bias; NT policy),
// source-XOR-swizzled so the row-varying read (4x ds_read_b128) is bank-uniform.
__global__ __launch_bounds__(256, 6) void attn_kernel(
    const u16* __restrict__ Q, const u16* __restrict__ Kd, const u16* __restrict__ Vt,
    const float* __restrict__ bias, float* __restrict__ Part)
{
  __shared__ u16 P[4][16 * 64];            // 8 KB: per-wave P^T tiles
  __shared__ float BiasS[2][2][16 * 64];   // 16 KB: [dbuf][q-half tile][16x64]
  const int lane = threadIdx.x & 63;
  const int wv = threadIdx.x >> 6;
  const int quad = lane >> 4, l15 = lane & 15;
  const int L  = (blockIdx.x & 7) * 256 + (blockIdx.x >> 3);  // XCD-contiguous
  const int h  = L >> 7;
  const int ks = (L >> 6) & 1;
  const int qg = L & 63;
  const int q0 = qg * 32;                 // block covers head-rows [q0, q0+32)
  const int b  = wv & 1;                  // wave's batch
  const int qh = wv >> 1;                 // wave's q-half (16 rows)
  const int bh = b * 16 + h;
  const int qw = q0 + qh * 16;            // wave's first q-row
  const int ksBase = ks << 10;            // k in [ksBase, ksBase+1024)
  const long baseN = (long)bh << 17;      // bh * 2048 * 64

  // Q B-frags: col=l15 -> q = qw+l15; k-chunk quad*8 -> d
  bfrag qf0 = *(const bfrag*)(Q + baseN + (long)(qw + l15) * 64 + quad * 8);
  bfrag qf1 = *(const bfrag*)(Q + baseN + (long)(qw + l15) * 64 + 32 + quad * 8);

  facc o[4];                 // O^T: lane holds q=qw+l15, d = t*16 + quad*4 + r
  float m_i = -1e30f, l_i = 0.f;   // per-lane scalars (one q row per lane)
  facc zero = {0.f, 0.f, 0.f, 0.f};
#pragma unroll
  for (int t = 0; t < 4; ++t) o[t] = zero;

  const float* bh_bias = bias + ((long)h << 22) + ((long)q0 << 11);  // bias[h][q0][0]
  char* PwB = (char*)&P[wv][0];

  // Cooperative bias staging: wave (b, qh) stages chunks {b*2, b*2+1} of tile qh.
  // LDS stays linear for the DMA; SOURCE column carries the XOR swizzle:
  // LDS[row][c] = bias[row][c ^ ((row&7)<<2)].
  auto stage = [&](int buf, int kk) {
#pragma unroll
    for (int cc = 0; cc < 2; ++cc) {
      const int c_ = b * 2 + cc;
      const int row_ = c_ * 4 + quad;
      gload_lds16f_nt(bh_bias + (long)(qh * 16 + row_) * 2048 + kk
                        + ((l15 * 4) ^ ((row_ & 7) << 2)),
                      &BiasS[buf][qh][0] + c_ * 256);
    }
  };

  stage(0, ksBase);   // prologue: tile for iteration 0

  for (int it = 0; it < 16; ++it) {
    const int k0 = ksBase + it * 64;
    __syncthreads();   // publish staged bias tile (vmcnt drain + barrier)

    // S^T = K Q^T: A = K rows (m=k), B = Q rows (n=q)
    facc s[4];
#pragma unroll
    for (int kt = 0; kt < 4; ++kt) {
      const u16* kb = Kd + baseN + (long)(k0 + kt * 16 + l15) * 64;
      bfrag kf0 = *(const bfrag*)(kb + quad * 8);
      bfrag kf1 = *(const bfrag*)(kb + 32 + quad * 8);
      facc z = zero;
      z = __builtin_amdgcn_mfma_f32_16x16x32_bf16(kf0, qf0, z, 0, 0, 0);
      z = __builtin_amdgcn_mfma_f32_16x16x32_bf16(kf1, qf1, z, 0, 0, 0);
      s[kt] = z;   // s[kt][r] = S[q=qw+l15][k = k0 + kt*16 + quad*4 + r]
    }

    // + rel_pos_bias: row = l15 (per-lane), cols kt*16+quad*4+{0..3}.
    // Swizzle preserves 4-contiguity: (C0 + r) ^ x = (C0 ^ x) + r for x mult of 4.
    const float* bs = &BiasS[it & 1][qh][0];
    const int bswz = (l15 & 7) << 2;
#pragma unroll
    for (int kt = 0; kt < 4; ++kt) {
      const facc bv = *(const facc*)(bs + l15 * 64 + ((kt * 16 + quad * 4) ^ bswz));
#pragma unroll
      for (int r = 0; r < 4; ++r) s[kt][r] += bv[r];
    }

    // issue next tile's staging (cover = softmax + P + PV until next barrier)
    if (it + 1 < 16) stage((it + 1) & 1, k0 + 64);

    // wave-parallel online softmax (per-lane row): in-lane tree + 2 shfl
    float mk[4];
#pragma unroll
    for (int kt = 0; kt < 4; ++kt)
      mk[kt] = fmaxf(fmaxf(s[kt][0], s[kt][1]), fmaxf(s[kt][2], s[kt][3]));
    float mx = fmaxf(fmaxf(mk[0], mk[1]), fmaxf(mk[2], mk[3]));
    mx = fmaxf(mx, __shfl_xor(mx, 16));
    mx = fmaxf(mx, __shfl_xor(mx, 32));
    const float mn = fmaxf(m_i, mx);
    const float alpha = exp2f((m_i - mn) * LOG2E);
    m_i = mn;

    float sum = 0.f;
#pragma unroll
    for (int kt = 0; kt < 4; ++kt) {
      const float p0 = exp2f((s[kt][0] - mn) * LOG2E);
      const float p1 = exp2f((s[kt][1] - mn) * LOG2E);
      const float p2 = exp2f((s[kt][2] - mn) * LOG2E);
      const float p3 = exp2f((s[kt][3] - mn) * LOG2E);
      s[kt][0] = p0; s[kt][1] = p1; s[kt][2] = p2; s[kt][3] = p3;
      sum += (p0 + p1) + (p2 + p3);
    }
    sum += __shfl_xor(sum, 16);
    sum += __shfl_xor(sum, 32);
    l_i = l_i * alpha + sum;
#pragma unroll
    for (int t = 0; t < 4; ++t)
#pragma unroll
      for (int r = 0; r < 4; ++r) o[t][r] *= alpha;

    // P^T -> LDS.  Element (K = k-k0, q) stored at byte
    //   (K>>5)*1024 + ((K>>3)&3)*256 + q*16 + (K&7)*2
    // so the B-frag read (K = p*32 + quad*8 + j, q = l15) is PwB + p*1024 + lane*16.
    // Lane holds K = kt*16 + quad*4 + r  ->  r=0..3 pack into one ds_write_b64.
#pragma unroll
    for (int kt = 0; kt < 4; ++kt) {
      ushort4 pk;
      pk.x = f2bf(s[kt][0]); pk.y = f2bf(s[kt][1]);
      pk.z = f2bf(s[kt][2]); pk.w = f2bf(s[kt][3]);
      const int bo = (kt >> 1) * 1024 + (((kt * 2) + (quad >> 1)) & 3) * 256
                   + l15 * 16 + (quad & 1) * 8;
      *(ushort4*)(PwB + bo) = pk;
    }

    // O^T += V^T P^T over both 32-key chunks (A = V^T rows d, B = P^T cols q)
#pragma unroll
    for (int p = 0; p < 2; ++p) {
      bfrag pfp = *(const bfrag*)(PwB + p * 1024 + lane * 16);
#pragma unroll
      for (int t = 0; t < 4; ++t) {
        bfrag vf = *(const bfrag*)(Vt + baseN + (((long)(t * 16 + l15)) << 11)
                                   + k0 + p * 32 + quad * 8);
        o[t] = __builtin_amdgcn_mfma_f32_16x16x32_bf16(vf, pfp, o[t], 0, 0, 0);
      }
    }
  }

  // partial epilogue: unnormalized O^T + (m,l).  Part row stride 80 f32.
  // Lane owns row q = qw+l15 -> 4 x float4 stores + one float2 (m,l) from quad 0.
  const long prBase = ((long)ks * 65536 + (long)bh * 2048 + qw) * 80;
  float* prow = Part + prBase + (long)l15 * 80;
#pragma unroll
  for (int t = 0; t < 4; ++t)
    *(facc*)(prow + t * 16 + quad * 4) = o[t];
  if (quad == 0) {
    float2 ml; ml.x = m_i; ml.y = l_i;
    *(float2*)(prow + 64) = ml;
  }
}

// Kernel 2b: merge the two K-half partials -> AO bf16 [B,N,H*D]
__global__ __launch_bounds__(256) void combine_kernel(
    const float* __restrict__ Part, u16* __restrict__ AO)
{
  const int lane = threadIdx.x & 63;
  const int wv = threadIdx.x >> 6;
  const long row = (long)blockIdx.x * 4 + wv;   // 0..65535 = bh*2048 + q
  const int bh = (int)(row >> 11);
  const int q  = (int)(row & 2047);
  const int b = bh >> 4, h = bh & 15;
  const float* p0 = Part + row * 80;
  const float* p1 = Part + (row + 65536) * 80;
  const float o0 = p0[lane], o1 = p1[lane];
  const float m0 = p0[64], l0 = p0[65];
  const float m1 = p1[64], l1 = p1[65];
  const float m = fmaxf(m0, m1);
  const float w0 = exp2f((m0 - m) * LOG2E);
  const float w1 = exp2f((m1 - m) * LOG2E);
  const float ov = (o0 * w0 + o1 * w1) / (l0 * w0 + l1 * w1);
  AO[(((long)(b * 2048 + q)) << 10) + h * 64 + lane] = f2bf(ov);
}

// Kernel 3: out = AO @ proj_w^T + proj_b  (f32 output)
__global__ __launch_bounds__(256) void proj_kernel(
    const u16* __restrict__ Ain, const u16* __restrict__ w,
    const float* __restrict__ pb, float* __restrict__ out)
{
  __shared__ u16 As[128 * 32];
  __shared__ u16 Bs[128 * 32];
  facc acc[4][4];
  const int m0 = blockIdx.y * 128;
  const int n0 = blockIdx.x * 128;
  gemm128_bt(Ain, w, 1024, m0, n0, As, Bs, acc);

  const int lane = threadIdx.x & 63;
  const int wv = threadIdx.x >> 6;
  const int quad = lane >> 4, l15 = lane & 15;
  const int wm = wv >> 1, wn = wv & 1;
#pragma unroll
  for (int j = 0; j < 4; ++j) {
    const int n_g = n0 + wn * 64 + j * 16 + l15;
    const float pbv = pb[n_g];
#pragma unroll
    for (int i = 0; i < 4; ++i) {
      const int mg0 = m0 + wm * 64 + i * 16 + quad * 4;
#pragma unroll
      for (int r = 0; r < 4; ++r)
        out[(((long)(mg0 + r)) << 10) + n_g] = acc[i][j][r] + pbv;
    }
  }
}

extern "C" void kernel_launch(void* const* d_in, const int* in_sizes, int n_in,
                              void* d_out, int out_size, void* d_ws, size_t ws_size,
                              hipStream_t stream)
{
  const float* x    = (const float*)d_in[0];   // [2,2048,1024] f32
  const float* bias = (const float*)d_in[1];   // [16,2048,2048] f32
  const float* qkvw = (const float*)d_in[2];   // [3072,1024] f32
  const float* qb   = (const float*)d_in[3];   // [1024] f32
  const float* vb   = (const float*)d_in[4];   // [1024] f32
  const float* pw   = (const float*)d_in[5];   // [1024,1024] f32
  const float* pb   = (const float*)d_in[6];   // [1024] f32
  float* out = (float*)d_out;                  // [2,2048,1024] f32

  char* ws = (char*)d_ws;                      // 88 MiB used
  u16* Q    = (u16*)(ws);                                  // [B,H,N,D]  8 MiB
  u16* Kd   = (u16*)(ws + (size_t)8  * 1024 * 1024);       // [B,H,N,D]  8 MiB
  u16* Vt   = (u16*)(ws + (size_t)16 * 1024 * 1024);       // [B,H,D,N]  8 MiB
  u16* AO   = (u16*)(ws + (size_t)24 * 1024 * 1024);       // [B,N,C]    8 MiB
  u16* xb   = (u16*)(ws + (size_t)32 * 1024 * 1024);       // x bf16     8 MiB
  u16* qwb  = (u16*)(ws + (size_t)40 * 1024 * 1024);       // qkv_w bf16 6 MiB
  u16* pwb  = (u16*)(ws + (size_t)46 * 1024 * 1024);       // proj_w bf16 2 MiB
  float* Part = (float*)(ws + (size_t)48 * 1024 * 1024);   // [2][32][2048][80] f32 40 MiB

  hipLaunchKernelGGL(convert_kernel, dim3(1024), dim3(256), 0, stream,
                     x, qkvw, pw, xb, qwb, pwb);
  hipLaunchKernelGGL(qkv_gemm_kernel, dim3(24, 32), dim3(256), 0, stream,
                     xb, qwb, qb, vb, Q, Kd, Vt);
  hipLaunchKernelGGL(attn_kernel, dim3(2048), dim3(256), 0, stream,
                     Q, Kd, Vt, bias, Part);
  hipLaunchKernelGGL(combine_kernel, dim3(16384), dim3(256), 0, stream,
                     Part, AO);
  hipLaunchKernelGGL(proj_kernel, dim3(8, 32), dim3(256), 0, stream,
                     AO, pwb, pb, out);
}